// Round 1
// baseline (293.499 us; speedup 1.0000x reference)
//
#include <hip/hip_runtime.h>
#include <hip/hip_bf16.h>

#define NN 8192
#define SD 512
#define HID 128
#define DE 128
#define KP1 11
#define EPSF 0.001f

using short8 = __attribute__((ext_vector_type(8))) short;
using f32x4 = __attribute__((ext_vector_type(4))) float;

// ---------------- Kernel 1: x = relu(s@W1^T + b1) @ W2^T + b2 ; xb = bf16(x); sqb = ||xb||^2
__global__ __launch_bounds__(256) void mlp_kernel(
    const float* __restrict__ s, const float* __restrict__ W1,
    const float* __restrict__ b1, const float* __restrict__ W2,
    const float* __restrict__ b2, __hip_bfloat16* __restrict__ xb,
    float* __restrict__ sqb)
{
    __shared__ float stile[16 * 512];   // 32 KB: 16 s-rows
    __shared__ float wtile[128 * 68];   // 34.8 KB: W chunk [128][64] pad->68 (bank spread)
    __shared__ float htile[16 * 132];   // 8.4 KB: relu(h)

    const int t = threadIdx.x;
    const int rb = blockIdx.x * 16;

    // load s tile (coalesced float4)
    const float4* sg = reinterpret_cast<const float4*>(s + (size_t)rb * SD);
    float4* sl = reinterpret_cast<float4*>(stile);
#pragma unroll
    for (int i = 0; i < 8; ++i) sl[t + i * 256] = sg[t + i * 256];

    const int r = t >> 4, cl = t & 15;   // 16 rows x 16 col-threads; cols c = cl + 16*j

    float acc[8];
#pragma unroll
    for (int j = 0; j < 8; ++j) acc[j] = 0.f;

    for (int dc = 0; dc < 8; ++dc) {
        __syncthreads();
#pragma unroll
        for (int i = 0; i < 8; ++i) {   // stage W1[:, dc*64 : +64]
            int f = t * 4 + i * 1024;
            int c = f >> 6, d = f & 63;
            float4 w = *reinterpret_cast<const float4*>(W1 + (size_t)c * SD + dc * 64 + d);
            *reinterpret_cast<float4*>(wtile + c * 68 + d) = w;
        }
        __syncthreads();
#pragma unroll
        for (int d = 0; d < 64; d += 4) {
            float4 s4 = *reinterpret_cast<const float4*>(stile + r * 512 + dc * 64 + d);
#pragma unroll
            for (int j = 0; j < 8; ++j) {
                float4 w4 = *reinterpret_cast<const float4*>(wtile + (cl + 16 * j) * 68 + d);
                acc[j] = fmaf(s4.x, w4.x, acc[j]);
                acc[j] = fmaf(s4.y, w4.y, acc[j]);
                acc[j] = fmaf(s4.z, w4.z, acc[j]);
                acc[j] = fmaf(s4.w, w4.w, acc[j]);
            }
        }
    }
    // bias + relu -> htile
#pragma unroll
    for (int j = 0; j < 8; ++j) {
        int c = cl + 16 * j;
        htile[r * 132 + c] = fmaxf(acc[j] + b1[c], 0.f);
    }

    float acc2[8];
#pragma unroll
    for (int j = 0; j < 8; ++j) acc2[j] = 0.f;
    for (int hc = 0; hc < 2; ++hc) {
        __syncthreads();    // protects wtile reuse AND publishes htile on first iter
#pragma unroll
        for (int i = 0; i < 8; ++i) {   // stage W2[:, hc*64 : +64]
            int f = t * 4 + i * 1024;
            int c = f >> 6, d = f & 63;
            float4 w = *reinterpret_cast<const float4*>(W2 + (size_t)c * HID + hc * 64 + d);
            *reinterpret_cast<float4*>(wtile + c * 68 + d) = w;
        }
        __syncthreads();
#pragma unroll
        for (int d = 0; d < 64; d += 4) {
            float4 h4 = *reinterpret_cast<const float4*>(htile + r * 132 + hc * 64 + d);
#pragma unroll
            for (int j = 0; j < 8; ++j) {
                float4 w4 = *reinterpret_cast<const float4*>(wtile + (cl + 16 * j) * 68 + d);
                acc2[j] = fmaf(h4.x, w4.x, acc2[j]);
                acc2[j] = fmaf(h4.y, w4.y, acc2[j]);
                acc2[j] = fmaf(h4.z, w4.z, acc2[j]);
                acc2[j] = fmaf(h4.w, w4.w, acc2[j]);
            }
        }
    }

    // x -> bf16 round; sq from ROUNDED values (keeps dist2(i,i) ~ 0 consistent)
    float p = 0.f;
    ushort xv[8];
#pragma unroll
    for (int j = 0; j < 8; ++j) {
        int c = cl + 16 * j;
        float x = acc2[j] + b2[c];
        __hip_bfloat16 xbv = __float2bfloat16(x);
        float xf = __bfloat162float(xbv);
        p = fmaf(xf, xf, p);
        xv[j] = *reinterpret_cast<ushort*>(&xbv);
    }
#pragma unroll
    for (int off = 8; off >= 1; off >>= 1) p += __shfl_xor(p, off, 16);
    if (cl == 0) sqb[rb + r] = p;

    // stage bf16 x through LDS (reuse stile) for coalesced dwordx4 store
    __syncthreads();
    ushort* xs = reinterpret_cast<ushort*>(stile);
#pragma unroll
    for (int j = 0; j < 8; ++j) xs[r * 128 + cl + 16 * j] = xv[j];
    __syncthreads();
    const short8* xsv = reinterpret_cast<const short8*>(xs);
    short8* xg = reinterpret_cast<short8*>(reinterpret_cast<ushort*>(xb) + (size_t)rb * DE);
    xg[t] = xsv[t];
}

// ---------------- Kernel 2: per-row top-11 of dist^2 via swapped MFMA
// C[cand][query]: lane owns query col (lane&15), candidates vary by reg -> per-lane top-k.
__global__ __launch_bounds__(256) void knn_kernel(
    const ushort* __restrict__ xs, const float* __restrict__ sqb,
    float* __restrict__ part)
{
    const int bid = blockIdx.x;              // 512 = 128 row-groups x 4 cand-splits
    const int rid = bid >> 2, cid = bid & 3;
    const int t = threadIdx.x;
    const int w = t >> 6, l = t & 63;
    const int qbase = rid * 64 + w * 16;
    const int q = qbase + (l & 15);
    const int kk = (l >> 4) * 8;

    short8 bq[4];
#pragma unroll
    for (int kb = 0; kb < 4; ++kb)
        bq[kb] = *reinterpret_cast<const short8*>(xs + (size_t)q * DE + kb * 32 + kk);
    const float sqq = sqb[q];

    float m[KP1];
#pragma unroll
    for (int j = 0; j < KP1; ++j) m[j] = 1e30f;

    const int cstart = cid * 2048;
    for (int ct = 0; ct < 128; ++ct) {
        const int c0 = cstart + ct * 16;
        const ushort* arow = xs + (size_t)(c0 + (l & 15)) * DE + kk;
        short8 a[4];
#pragma unroll
        for (int kb = 0; kb < 4; ++kb)
            a[kb] = *reinterpret_cast<const short8*>(arow + kb * 32);
        f32x4 acc = {0.f, 0.f, 0.f, 0.f};
#pragma unroll
        for (int kb = 0; kb < 4; ++kb)
            acc = __builtin_amdgcn_mfma_f32_16x16x32_bf16(a[kb], bq[kb], acc, 0, 0, 0);
        const int cm = c0 + (l >> 4) * 4;
#pragma unroll
        for (int reg = 0; reg < 4; ++reg) {
            float d2 = fmaf(-2.0f, acc[reg], sqq + sqb[cm + reg]);
            if (d2 < m[KP1 - 1]) {   // sorted branchless insert (rare)
#pragma unroll
                for (int j = KP1 - 1; j >= 1; --j)
                    m[j] = fminf(fmaxf(d2, m[j - 1]), m[j]);
                m[0] = fminf(d2, m[0]);
            }
        }
    }
    // 16 chunks total: cid*4 + lane-group; column-major layout for coalesced merge reads
    const int chunk = cid * 4 + (l >> 4);
#pragma unroll
    for (int j = 0; j < KP1; ++j)
        part[(size_t)(chunk * KP1 + j) * NN + q] = m[j];
}

// ---------------- Kernel 3: merge 16 partial top-11 lists -> sum of 10 nearest dists
__global__ __launch_bounds__(256) void merge_kernel(
    const float* __restrict__ part, float* __restrict__ sumk)
{
    const int row = blockIdx.x * 256 + threadIdx.x;
    float m[KP1];
#pragma unroll
    for (int j = 0; j < KP1; ++j) m[j] = 1e30f;
    for (int ch = 0; ch < 16; ++ch) {
#pragma unroll
        for (int j = 0; j < KP1; ++j) {
            float d2 = part[(size_t)(ch * KP1 + j) * NN + row];
            if (d2 < m[KP1 - 1]) {
#pragma unroll
                for (int jj = KP1 - 1; jj >= 1; --jj)
                    m[jj] = fminf(fmaxf(d2, m[jj - 1]), m[jj]);
                m[0] = fminf(d2, m[0]);
            } else break;   // chunk lists are sorted ascending
        }
    }
    // m[0] = self (~0, possibly tiny negative); drop it, sum sqrt of the next 10
    float sum = 0.f;
#pragma unroll
    for (int j = 1; j < KP1; ++j) sum += sqrtf(fmaxf(m[j], 1e-12f));
    sumk[row] = sum;
}

// ---------------- Kernel 4: deterministic mean over sumk -> q = EPS * mean^2
__global__ __launch_bounds__(256) void reduce_kernel(
    const float* __restrict__ sumk, float* __restrict__ qv)
{
    __shared__ float red[4];
    float p = 0.f;
    for (int i = threadIdx.x; i < NN; i += 256) p += sumk[i];
#pragma unroll
    for (int off = 32; off >= 1; off >>= 1) p += __shfl_xor(p, off, 64);
    if ((threadIdx.x & 63) == 0) red[threadIdx.x >> 6] = p;
    __syncthreads();
    if (threadIdx.x == 0) {
        float mean = (red[0] + red[1] + red[2] + red[3]) * (1.0f / NN);
        qv[0] = EPSF * mean * mean;
    }
}

// ---------------- Kernel 5: out = q / (s^2 + q)  ==  EPS / (s^2/mean^2 + EPS)
__global__ __launch_bounds__(256) void final_kernel(
    const float* __restrict__ sumk, const float* __restrict__ qv,
    float* __restrict__ out)
{
    const int i = blockIdx.x * 256 + threadIdx.x;
    const float qq = qv[0];
    const float sv = sumk[i];
    out[i] = qq / (fmaf(sv, sv, qq));
}

extern "C" void kernel_launch(void* const* d_in, const int* in_sizes, int n_in,
                              void* d_out, int out_size, void* d_ws, size_t ws_size,
                              hipStream_t stream)
{
    const float* s  = (const float*)d_in[0];
    const float* W1 = (const float*)d_in[1];
    const float* b1 = (const float*)d_in[2];
    const float* W2 = (const float*)d_in[3];
    const float* b2 = (const float*)d_in[4];
    // d_in[5] is k == 10 (fixed by problem spec); KP1 = 11 hardcoded.
    float* out = (float*)d_out;

    char* ws = (char*)d_ws;
    __hip_bfloat16* xb = (__hip_bfloat16*)ws;                       // 8192*128 bf16 = 2 MB
    float* sqb  = (float*)(ws + (size_t)NN * DE * 2);               // 32 KB
    float* part = sqb + NN;                                         // 16*11*8192 f32 = 5.63 MB
    float* sumk = part + (size_t)16 * KP1 * NN;                     // 32 KB
    float* qv   = sumk + NN;                                        // 4 B

    mlp_kernel<<<NN / 16, 256, 0, stream>>>(s, W1, b1, W2, b2, xb, sqb);
    knn_kernel<<<(NN / 64) * 4, 256, 0, stream>>>((const ushort*)xb, sqb, part);
    merge_kernel<<<NN / 256, 256, 0, stream>>>(part, sumk);
    reduce_kernel<<<1, 256, 0, stream>>>(sumk, qv);
    final_kernel<<<NN / 256, 256, 0, stream>>>(sumk, qv, out);
}

// Round 2
// 241.288 us; speedup vs baseline: 1.2164x; 1.2164x over previous
//
#include <hip/hip_runtime.h>
#include <hip/hip_bf16.h>

#define NN 8192
#define SD 512
#define HID 128
#define DE 128
#define KP1 11
#define EPSF 0.001f
#define NSPLIT 8
#define NCHUNK (NSPLIT * 4)   // 32 partial lists per row

using short8 = __attribute__((ext_vector_type(8))) short;
using f32x4 = __attribute__((ext_vector_type(4))) float;

// ---------------- Kernel 1: x = relu(s@W1^T + b1) @ W2^T + b2 ; xb = bf16(x); sqb = ||xb||^2
__global__ __launch_bounds__(256) void mlp_kernel(
    const float* __restrict__ s, const float* __restrict__ W1,
    const float* __restrict__ b1, const float* __restrict__ W2,
    const float* __restrict__ b2, __hip_bfloat16* __restrict__ xb,
    float* __restrict__ sqb)
{
    __shared__ float stile[16 * 512];   // 32 KB: 16 s-rows
    __shared__ float wtile[128 * 68];   // 34.8 KB: W chunk [128][64] pad->68
    __shared__ float htile[16 * 132];   // 8.4 KB: relu(h)

    const int t = threadIdx.x;
    const int rb = blockIdx.x * 16;

    const float4* sg = reinterpret_cast<const float4*>(s + (size_t)rb * SD);
    float4* sl = reinterpret_cast<float4*>(stile);
#pragma unroll
    for (int i = 0; i < 8; ++i) sl[t + i * 256] = sg[t + i * 256];

    const int r = t >> 4, cl = t & 15;

    float acc[8];
#pragma unroll
    for (int j = 0; j < 8; ++j) acc[j] = 0.f;

    for (int dc = 0; dc < 8; ++dc) {
        __syncthreads();
#pragma unroll
        for (int i = 0; i < 8; ++i) {
            int f = t * 4 + i * 1024;
            int c = f >> 6, d = f & 63;
            float4 w = *reinterpret_cast<const float4*>(W1 + (size_t)c * SD + dc * 64 + d);
            *reinterpret_cast<float4*>(wtile + c * 68 + d) = w;
        }
        __syncthreads();
#pragma unroll
        for (int d = 0; d < 64; d += 4) {
            float4 s4 = *reinterpret_cast<const float4*>(stile + r * 512 + dc * 64 + d);
#pragma unroll
            for (int j = 0; j < 8; ++j) {
                float4 w4 = *reinterpret_cast<const float4*>(wtile + (cl + 16 * j) * 68 + d);
                acc[j] = fmaf(s4.x, w4.x, acc[j]);
                acc[j] = fmaf(s4.y, w4.y, acc[j]);
                acc[j] = fmaf(s4.z, w4.z, acc[j]);
                acc[j] = fmaf(s4.w, w4.w, acc[j]);
            }
        }
    }
#pragma unroll
    for (int j = 0; j < 8; ++j) {
        int c = cl + 16 * j;
        htile[r * 132 + c] = fmaxf(acc[j] + b1[c], 0.f);
    }

    float acc2[8];
#pragma unroll
    for (int j = 0; j < 8; ++j) acc2[j] = 0.f;
    for (int hc = 0; hc < 2; ++hc) {
        __syncthreads();
#pragma unroll
        for (int i = 0; i < 8; ++i) {
            int f = t * 4 + i * 1024;
            int c = f >> 6, d = f & 63;
            float4 w = *reinterpret_cast<const float4*>(W2 + (size_t)c * HID + hc * 64 + d);
            *reinterpret_cast<float4*>(wtile + c * 68 + d) = w;
        }
        __syncthreads();
#pragma unroll
        for (int d = 0; d < 64; d += 4) {
            float4 h4 = *reinterpret_cast<const float4*>(htile + r * 132 + hc * 64 + d);
#pragma unroll
            for (int j = 0; j < 8; ++j) {
                float4 w4 = *reinterpret_cast<const float4*>(wtile + (cl + 16 * j) * 68 + d);
                acc2[j] = fmaf(h4.x, w4.x, acc2[j]);
                acc2[j] = fmaf(h4.y, w4.y, acc2[j]);
                acc2[j] = fmaf(h4.z, w4.z, acc2[j]);
                acc2[j] = fmaf(h4.w, w4.w, acc2[j]);
            }
        }
    }

    float p = 0.f;
    ushort xv[8];
#pragma unroll
    for (int j = 0; j < 8; ++j) {
        int c = cl + 16 * j;
        float x = acc2[j] + b2[c];
        __hip_bfloat16 xbv = __float2bfloat16(x);
        float xf = __bfloat162float(xbv);
        p = fmaf(xf, xf, p);
        xv[j] = *reinterpret_cast<ushort*>(&xbv);
    }
#pragma unroll
    for (int off = 8; off >= 1; off >>= 1) p += __shfl_xor(p, off, 16);
    if (cl == 0) sqb[rb + r] = p;

    __syncthreads();
    ushort* xs = reinterpret_cast<ushort*>(stile);
#pragma unroll
    for (int j = 0; j < 8; ++j) xs[r * 128 + cl + 16 * j] = xv[j];
    __syncthreads();
    const short8* xsv = reinterpret_cast<const short8*>(xs);
    short8* xg = reinterpret_cast<short8*>(reinterpret_cast<ushort*>(xb) + (size_t)rb * DE);
    xg[t] = xsv[t];
}

// ---------------- Kernel 2: per-row top-11 of d2' = sq[c] - 2*dot (sqq constant per row,
// dropped during scan). Swapped MFMA: lane owns query col; branchless sorted insert;
// register double-buffered candidate tiles (32 cands/iter).
__global__ __launch_bounds__(256) void knn_kernel(
    const ushort* __restrict__ xs, const float* __restrict__ sqb,
    float* __restrict__ part)
{
    const int bid = blockIdx.x;              // 1024 = 128 row-groups x 8 cand-splits
    const int rid = bid >> 3, cid = bid & 7;
    const int t = threadIdx.x;
    const int w = t >> 6, l = t & 63;
    const int q = rid * 64 + w * 16 + (l & 15);
    const int lg = l >> 4;                   // lane group 0..3
    const int kk = lg * 8;

    short8 bq[4];
#pragma unroll
    for (int kb = 0; kb < 4; ++kb)
        bq[kb] = *reinterpret_cast<const short8*>(xs + (size_t)q * DE + kb * 32 + kk);

    float m[KP1];
#pragma unroll
    for (int j = 0; j < KP1; ++j) m[j] = 1e30f;

    const int cstart = cid * (NN / NSPLIT);  // 1024 candidates per block
    const ushort* abase = xs + (size_t)(cstart + (l & 15)) * DE + kk;
    const float* sbase = sqb + cstart + lg * 4;

    short8 aA[8], aB[8];
    float4 sA[2], sB[2];

    // NOTE: last prefetch (tile 32) reads past xs into sqb/part region of d_ws —
    // mapped memory, values never used.
#define LOADT(A, S, it_) do { \
    const ushort* p_ = abase + (size_t)(it_) * 32 * DE; \
    _Pragma("unroll") \
    for (int h_ = 0; h_ < 8; ++h_) \
        (A)[h_] = *reinterpret_cast<const short8*>(p_ + (h_ >> 2) * 16 * DE + (h_ & 3) * 32); \
    (S)[0] = *reinterpret_cast<const float4*>(sbase + (it_) * 32); \
    (S)[1] = *reinterpret_cast<const float4*>(sbase + (it_) * 32 + 16); \
} while (0)

    auto ins = [&](float d2) {
#pragma unroll
        for (int j = KP1 - 1; j >= 1; --j)
            m[j] = fminf(fmaxf(d2, m[j - 1]), m[j]);
        m[0] = fminf(d2, m[0]);
    };

#define PROC(A, S) do { \
    f32x4 acc0 = {0.f, 0.f, 0.f, 0.f}, acc1 = {0.f, 0.f, 0.f, 0.f}; \
    _Pragma("unroll") \
    for (int kb_ = 0; kb_ < 4; ++kb_) { \
        acc0 = __builtin_amdgcn_mfma_f32_16x16x32_bf16((A)[kb_], bq[kb_], acc0, 0, 0, 0); \
        acc1 = __builtin_amdgcn_mfma_f32_16x16x32_bf16((A)[4 + kb_], bq[kb_], acc1, 0, 0, 0); \
    } \
    ins(fmaf(-2.f, acc0[0], (S)[0].x)); \
    ins(fmaf(-2.f, acc0[1], (S)[0].y)); \
    ins(fmaf(-2.f, acc0[2], (S)[0].z)); \
    ins(fmaf(-2.f, acc0[3], (S)[0].w)); \
    ins(fmaf(-2.f, acc1[0], (S)[1].x)); \
    ins(fmaf(-2.f, acc1[1], (S)[1].y)); \
    ins(fmaf(-2.f, acc1[2], (S)[1].z)); \
    ins(fmaf(-2.f, acc1[3], (S)[1].w)); \
} while (0)

    LOADT(aA, sA, 0);
    for (int it = 0; it < 32; it += 2) {
        LOADT(aB, sB, it + 1);
        PROC(aA, sA);
        LOADT(aA, sA, it + 2);
        PROC(aB, sB);
    }
#undef LOADT
#undef PROC

    const int chunk = cid * 4 + lg;
#pragma unroll
    for (int j = 0; j < KP1; ++j)
        part[(size_t)(chunk * KP1 + j) * NN + q] = m[j];
}

// ---------------- Kernel 3: merge 32 partial top-11 lists -> sumk[row]; block partial sums
__global__ __launch_bounds__(256) void merge_kernel(
    const float* __restrict__ part, const float* __restrict__ sqb,
    float* __restrict__ sumk, float* __restrict__ psum)
{
    const int row = blockIdx.x * 256 + threadIdx.x;
    float m[KP1];
#pragma unroll
    for (int j = 0; j < KP1; ++j) m[j] = 1e30f;
#pragma unroll 4
    for (int ch = 0; ch < NCHUNK; ++ch) {
#pragma unroll
        for (int j = 0; j < KP1; ++j) {
            float d2 = part[(size_t)(ch * KP1 + j) * NN + row];
#pragma unroll
            for (int jj = KP1 - 1; jj >= 1; --jj)
                m[jj] = fminf(fmaxf(d2, m[jj - 1]), m[jj]);
            m[0] = fminf(d2, m[0]);
        }
    }
    // m[0] = self (= -sqq); drop it; dist^2 = d2' + sqq
    const float sqq = sqb[row];
    float sum = 0.f;
#pragma unroll
    for (int j = 1; j < KP1; ++j)
        sum += sqrtf(fmaxf(m[j] + sqq, 1e-12f));
    sumk[row] = sum;

    float p = sum;
#pragma unroll
    for (int off = 32; off >= 1; off >>= 1) p += __shfl_xor(p, off, 64);
    __shared__ float red[4];
    if ((threadIdx.x & 63) == 0) red[threadIdx.x >> 6] = p;
    __syncthreads();
    if (threadIdx.x == 0) psum[blockIdx.x] = red[0] + red[1] + red[2] + red[3];
}

// ---------------- Kernel 4: mean over 32 partials -> q = EPS * mean^2
__global__ void reduce_kernel(const float* __restrict__ psum, float* __restrict__ qv)
{
    const int t = threadIdx.x;
    float p = (t < 32) ? psum[t] : 0.f;
#pragma unroll
    for (int off = 32; off >= 1; off >>= 1) p += __shfl_xor(p, off, 64);
    if (t == 0) {
        float mean = p * (1.0f / NN);
        qv[0] = EPSF * mean * mean;
    }
}

// ---------------- Kernel 5: out = q / (s^2 + q)
__global__ __launch_bounds__(256) void final_kernel(
    const float* __restrict__ sumk, const float* __restrict__ qv,
    float* __restrict__ out)
{
    const int i = blockIdx.x * 256 + threadIdx.x;
    const float qq = qv[0];
    const float sv = sumk[i];
    out[i] = qq / (fmaf(sv, sv, qq));
}

extern "C" void kernel_launch(void* const* d_in, const int* in_sizes, int n_in,
                              void* d_out, int out_size, void* d_ws, size_t ws_size,
                              hipStream_t stream)
{
    const float* s  = (const float*)d_in[0];
    const float* W1 = (const float*)d_in[1];
    const float* b1 = (const float*)d_in[2];
    const float* W2 = (const float*)d_in[3];
    const float* b2 = (const float*)d_in[4];
    float* out = (float*)d_out;

    char* ws = (char*)d_ws;
    __hip_bfloat16* xb = (__hip_bfloat16*)ws;                       // 2 MB
    float* sqb  = (float*)(ws + (size_t)NN * DE * 2);               // 32 KB
    float* part = sqb + NN;                                         // 32*11*8192*4 = 11.5 MB
    float* sumk = part + (size_t)NCHUNK * KP1 * NN;                 // 32 KB
    float* psum = sumk + NN;                                        // 128 B
    float* qv   = psum + 32;                                        // 4 B

    mlp_kernel<<<NN / 16, 256, 0, stream>>>(s, W1, b1, W2, b2, xb, sqb);
    knn_kernel<<<(NN / 64) * NSPLIT, 256, 0, stream>>>((const ushort*)xb, sqb, part);
    merge_kernel<<<NN / 256, 256, 0, stream>>>(part, sqb, sumk, psum);
    reduce_kernel<<<1, 64, 0, stream>>>(psum, qv);
    final_kernel<<<NN / 256, 256, 0, stream>>>(sumk, qv, out);
}

// Round 3
// 148.355 us; speedup vs baseline: 1.9784x; 1.6264x over previous
//
#include <hip/hip_runtime.h>
#include <hip/hip_bf16.h>

#define NN 8192
#define SD 512
#define HID 128
#define DE 128
#define KP1 11
#define EPSF 0.001f
#define NSPLIT 16
#define NCHUNK NSPLIT        // in-kernel lane-group merge -> 16 partial lists per row
#define TILE 32
#define NTILE ((NN / NSPLIT) / TILE)   // 16 tiles of 32 candidates per block

using short8 = __attribute__((ext_vector_type(8))) short;
using f32x4 = __attribute__((ext_vector_type(4))) float;

// ---------------- Kernel 1: x = relu(s@W1^T + b1) @ W2^T + b2 ; xb = bf16(x); sqb = ||xb||^2
__global__ __launch_bounds__(256) void mlp_kernel(
    const float* __restrict__ s, const float* __restrict__ W1,
    const float* __restrict__ b1, const float* __restrict__ W2,
    const float* __restrict__ b2, __hip_bfloat16* __restrict__ xb,
    float* __restrict__ sqb)
{
    __shared__ float stile[16 * 512];
    __shared__ float wtile[128 * 68];
    __shared__ float htile[16 * 132];

    const int t = threadIdx.x;
    const int rb = blockIdx.x * 16;

    const float4* sg = reinterpret_cast<const float4*>(s + (size_t)rb * SD);
    float4* sl = reinterpret_cast<float4*>(stile);
#pragma unroll
    for (int i = 0; i < 8; ++i) sl[t + i * 256] = sg[t + i * 256];

    const int r = t >> 4, cl = t & 15;

    float acc[8];
#pragma unroll
    for (int j = 0; j < 8; ++j) acc[j] = 0.f;

    for (int dc = 0; dc < 8; ++dc) {
        __syncthreads();
#pragma unroll
        for (int i = 0; i < 8; ++i) {
            int f = t * 4 + i * 1024;
            int c = f >> 6, d = f & 63;
            float4 w = *reinterpret_cast<const float4*>(W1 + (size_t)c * SD + dc * 64 + d);
            *reinterpret_cast<float4*>(wtile + c * 68 + d) = w;
        }
        __syncthreads();
#pragma unroll
        for (int d = 0; d < 64; d += 4) {
            float4 s4 = *reinterpret_cast<const float4*>(stile + r * 512 + dc * 64 + d);
#pragma unroll
            for (int j = 0; j < 8; ++j) {
                float4 w4 = *reinterpret_cast<const float4*>(wtile + (cl + 16 * j) * 68 + d);
                acc[j] = fmaf(s4.x, w4.x, acc[j]);
                acc[j] = fmaf(s4.y, w4.y, acc[j]);
                acc[j] = fmaf(s4.z, w4.z, acc[j]);
                acc[j] = fmaf(s4.w, w4.w, acc[j]);
            }
        }
    }
#pragma unroll
    for (int j = 0; j < 8; ++j) {
        int c = cl + 16 * j;
        htile[r * 132 + c] = fmaxf(acc[j] + b1[c], 0.f);
    }

    float acc2[8];
#pragma unroll
    for (int j = 0; j < 8; ++j) acc2[j] = 0.f;
    for (int hc = 0; hc < 2; ++hc) {
        __syncthreads();
#pragma unroll
        for (int i = 0; i < 8; ++i) {
            int f = t * 4 + i * 1024;
            int c = f >> 6, d = f & 63;
            float4 w = *reinterpret_cast<const float4*>(W2 + (size_t)c * HID + hc * 64 + d);
            *reinterpret_cast<float4*>(wtile + c * 68 + d) = w;
        }
        __syncthreads();
#pragma unroll
        for (int d = 0; d < 64; d += 4) {
            float4 h4 = *reinterpret_cast<const float4*>(htile + r * 132 + hc * 64 + d);
#pragma unroll
            for (int j = 0; j < 8; ++j) {
                float4 w4 = *reinterpret_cast<const float4*>(wtile + (cl + 16 * j) * 68 + d);
                acc2[j] = fmaf(h4.x, w4.x, acc2[j]);
                acc2[j] = fmaf(h4.y, w4.y, acc2[j]);
                acc2[j] = fmaf(h4.z, w4.z, acc2[j]);
                acc2[j] = fmaf(h4.w, w4.w, acc2[j]);
            }
        }
    }

    float p = 0.f;
    ushort xv[8];
#pragma unroll
    for (int j = 0; j < 8; ++j) {
        int c = cl + 16 * j;
        float x = acc2[j] + b2[c];
        __hip_bfloat16 xbv = __float2bfloat16(x);
        float xf = __bfloat162float(xbv);
        p = fmaf(xf, xf, p);
        xv[j] = *reinterpret_cast<ushort*>(&xbv);
    }
#pragma unroll
    for (int off = 8; off >= 1; off >>= 1) p += __shfl_xor(p, off, 16);
    if (cl == 0) sqb[rb + r] = p;

    __syncthreads();
    ushort* xs = reinterpret_cast<ushort*>(stile);
#pragma unroll
    for (int j = 0; j < 8; ++j) xs[r * 128 + cl + 16 * j] = xv[j];
    __syncthreads();
    const short8* xsv = reinterpret_cast<const short8*>(xs);
    short8* xg = reinterpret_cast<short8*>(reinterpret_cast<ushort*>(xb) + (size_t)rb * DE);
    xg[t] = xsv[t];
}

// ---------------- Kernel 2: per-row top-11 of d2' = sq[c] - 2*dot. Swapped MFMA,
// LDS-staged swizzled candidate tiles (double-buffered), med3 sorted insert.
__global__ __launch_bounds__(256, 6) void knn_kernel(
    const ushort* __restrict__ xs, const float* __restrict__ sqb,
    float* __restrict__ part)
{
    __shared__ __align__(16) ushort lbuf[2][TILE * DE];   // 2 x 8KB

    const int bid = blockIdx.x;              // 2048 = 128 row-groups x 16 cand-splits
    const int rid = bid >> 4, cid = bid & 15;
    const int t = threadIdx.x;
    const int w = t >> 6, l = t & 63;
    const int q16 = l & 15, lg = l >> 4;
    const int q = rid * 64 + w * 16 + q16;
    const int kk = lg * 8;
    const int cstart = cid * (NN / NSPLIT);  // 512 candidates per block

    // query B-fragments (held in regs the whole kernel)
    short8 bq[4];
#pragma unroll
    for (int kb = 0; kb < 4; ++kb)
        bq[kb] = *reinterpret_cast<const short8*>(xs + (size_t)q * DE + kb * 32 + kk);

    float m[KP1];
#pragma unroll
    for (int j = 0; j < KP1; ++j) m[j] = 1e30f;

    // exact sorted insert: m sorted ascending => min(max(d2,m[j-1]),m[j]) == med3
    auto ins = [&](float d2) {
#pragma unroll
        for (int j = KP1 - 1; j >= 1; --j)
            m[j] = __builtin_amdgcn_fmed3f(d2, m[j - 1], m[j]);
        m[0] = fminf(d2, m[0]);
    };

    // staging: thread t owns 16B slots s0=t, s1=t+256 of the 512-slot (8KB) tile.
    // global src linear (row=s>>4, col16=s&15); LDS dst col16 XOR-swizzled by row&7.
    const int s0 = t, s1 = t + 256;
    const int g0 = (s0 >> 4) * DE + (s0 & 15) * 8;          // ushort units
    const int g1 = (s1 >> 4) * DE + (s1 & 15) * 8;
    const int d0 = ((s0 >> 4) * 16 + ((s0 & 15) ^ ((s0 >> 4) & 7))) * 8;
    const int d1 = ((s1 >> 4) * 16 + ((s1 & 15) ^ ((s1 >> 4) & 7))) * 8;

    short8 vS0, vS1;
#define STAGE_LOAD(tt_) do { \
    const ushort* sb_ = xs + (size_t)(cstart + (tt_) * TILE) * DE; \
    vS0 = *reinterpret_cast<const short8*>(sb_ + g0); \
    vS1 = *reinterpret_cast<const short8*>(sb_ + g1); \
} while (0)
#define STAGE_WRITE(nb_) do { \
    *reinterpret_cast<short8*>(&lbuf[nb_][d0]) = vS0; \
    *reinterpret_cast<short8*>(&lbuf[nb_][d1]) = vS1; \
} while (0)

    STAGE_LOAD(0);
    STAGE_WRITE(0);

    for (int tt = 0; tt < NTILE; ++tt) {
        __syncthreads();                     // publishes lbuf[tt&1]
        if (tt + 1 < NTILE) STAGE_LOAD(tt + 1);   // HBM/L2 latency hides under compute

        const int c0 = cstart + tt * TILE;
        float4 sv0 = *reinterpret_cast<const float4*>(sqb + c0 + lg * 4);
        float4 sv1 = *reinterpret_cast<const float4*>(sqb + c0 + 16 + lg * 4);

        const ushort* lb = lbuf[tt & 1];
        short8 fa[4], fb[4];
#pragma unroll
        for (int kb = 0; kb < 4; ++kb) {
            int col = (kb * 4 + lg) ^ (q16 & 7);
            fa[kb] = *reinterpret_cast<const short8*>(lb + (q16 * 16 + col) * 8);
            fb[kb] = *reinterpret_cast<const short8*>(lb + ((16 + q16) * 16 + col) * 8);
        }
        f32x4 acc0 = {0.f, 0.f, 0.f, 0.f}, acc1 = {0.f, 0.f, 0.f, 0.f};
#pragma unroll
        for (int kb = 0; kb < 4; ++kb) {
            acc0 = __builtin_amdgcn_mfma_f32_16x16x32_bf16(fa[kb], bq[kb], acc0, 0, 0, 0);
            acc1 = __builtin_amdgcn_mfma_f32_16x16x32_bf16(fb[kb], bq[kb], acc1, 0, 0, 0);
        }
        ins(fmaf(-2.f, acc0[0], sv0.x));
        ins(fmaf(-2.f, acc0[1], sv0.y));
        ins(fmaf(-2.f, acc0[2], sv0.z));
        ins(fmaf(-2.f, acc0[3], sv0.w));
        ins(fmaf(-2.f, acc1[0], sv1.x));
        ins(fmaf(-2.f, acc1[1], sv1.y));
        ins(fmaf(-2.f, acc1[2], sv1.z));
        ins(fmaf(-2.f, acc1[3], sv1.w));

        if (tt + 1 < NTILE) STAGE_WRITE((tt + 1) & 1);  // into the buffer just freed
    }
#undef STAGE_LOAD
#undef STAGE_WRITE

    // ---- in-kernel lane-group merge: 4 lists per q -> 1 list per (q, cid)
    __syncthreads();                          // all waves done reading lbuf
    float* mb = reinterpret_cast<float*>(lbuf);   // [4w][4lg][11][16q] = 11264 B
#pragma unroll
    for (int j = 0; j < KP1; ++j)
        mb[((w * 4 + lg) * KP1 + j) * 16 + q16] = m[j];
    __syncthreads();
    if (lg == 0) {                            // lanes 0..15 of each wave; q16 == l
#pragma unroll
        for (int g = 1; g < 4; ++g)
#pragma unroll
            for (int j = 0; j < KP1; ++j)
                ins(mb[((w * 4 + g) * KP1 + j) * 16 + q16]);
#pragma unroll
        for (int j = 0; j < KP1; ++j)
            part[(size_t)(cid * KP1 + j) * NN + q] = m[j];
    }
}

// ---------------- Kernel 3: merge 16 partial top-11 lists -> sumk[row]; block partial sums
__global__ __launch_bounds__(256) void merge_kernel(
    const float* __restrict__ part, const float* __restrict__ sqb,
    float* __restrict__ sumk, float* __restrict__ psum)
{
    const int row = blockIdx.x * 256 + threadIdx.x;
    float m[KP1];
#pragma unroll
    for (int j = 0; j < KP1; ++j) m[j] = 1e30f;
#pragma unroll
    for (int ch = 0; ch < NCHUNK; ++ch) {
#pragma unroll
        for (int j = 0; j < KP1; ++j) {
            float d2 = part[(size_t)(ch * KP1 + j) * NN + row];
#pragma unroll
            for (int jj = KP1 - 1; jj >= 1; --jj)
                m[jj] = __builtin_amdgcn_fmed3f(d2, m[jj - 1], m[jj]);
            m[0] = fminf(d2, m[0]);
        }
    }
    const float sqq = sqb[row];
    float sum = 0.f;
#pragma unroll
    for (int j = 1; j < KP1; ++j)
        sum += sqrtf(fmaxf(m[j] + sqq, 1e-12f));
    sumk[row] = sum;

    float p = sum;
#pragma unroll
    for (int off = 32; off >= 1; off >>= 1) p += __shfl_xor(p, off, 64);
    __shared__ float red[4];
    if ((threadIdx.x & 63) == 0) red[threadIdx.x >> 6] = p;
    __syncthreads();
    if (threadIdx.x == 0) psum[blockIdx.x] = red[0] + red[1] + red[2] + red[3];
}

// ---------------- Kernel 4: mean over 32 partials -> q = EPS * mean^2
__global__ void reduce_kernel(const float* __restrict__ psum, float* __restrict__ qv)
{
    const int t = threadIdx.x;
    float p = (t < 32) ? psum[t] : 0.f;
#pragma unroll
    for (int off = 32; off >= 1; off >>= 1) p += __shfl_xor(p, off, 64);
    if (t == 0) {
        float mean = p * (1.0f / NN);
        qv[0] = EPSF * mean * mean;
    }
}

// ---------------- Kernel 5: out = q / (s^2 + q)
__global__ __launch_bounds__(256) void final_kernel(
    const float* __restrict__ sumk, const float* __restrict__ qv,
    float* __restrict__ out)
{
    const int i = blockIdx.x * 256 + threadIdx.x;
    const float qq = qv[0];
    const float sv = sumk[i];
    out[i] = qq / (fmaf(sv, sv, qq));
}

extern "C" void kernel_launch(void* const* d_in, const int* in_sizes, int n_in,
                              void* d_out, int out_size, void* d_ws, size_t ws_size,
                              hipStream_t stream)
{
    const float* s  = (const float*)d_in[0];
    const float* W1 = (const float*)d_in[1];
    const float* b1 = (const float*)d_in[2];
    const float* W2 = (const float*)d_in[3];
    const float* b2 = (const float*)d_in[4];
    float* out = (float*)d_out;

    char* ws = (char*)d_ws;
    __hip_bfloat16* xb = (__hip_bfloat16*)ws;                       // 2 MB
    float* sqb  = (float*)(ws + (size_t)NN * DE * 2);               // 32 KB
    float* part = sqb + NN;                                         // 16*11*8192*4 = 5.6 MB
    float* sumk = part + (size_t)NCHUNK * KP1 * NN;                 // 32 KB
    float* psum = sumk + NN;                                        // 128 B
    float* qv   = psum + 32;                                        // 4 B

    mlp_kernel<<<NN / 16, 256, 0, stream>>>(s, W1, b1, W2, b2, xb, sqb);
    knn_kernel<<<(NN / 64) * NSPLIT, 256, 0, stream>>>((const ushort*)xb, sqb, part);
    merge_kernel<<<NN / 256, 256, 0, stream>>>(part, sqb, sumk, psum);
    reduce_kernel<<<1, 64, 0, stream>>>(psum, qv);
    final_kernel<<<NN / 256, 256, 0, stream>>>(sumk, qv, out);
}

// Round 4
// 85.770 us; speedup vs baseline: 3.4219x; 1.7297x over previous
//
#include <hip/hip_runtime.h>
#include <hip/hip_bf16.h>

#define NN 8192
#define SD 512
#define HID 128
#define DE 128
#define KP1 11
#define EPSF 0.001f
#define NSPLIT 16
#define NCHUNK NSPLIT        // 16 partial lists per row
#define TILE 32
#define NTILE ((NN / NSPLIT) / TILE)

using short8 = __attribute__((ext_vector_type(8))) short;
using f32x4 = __attribute__((ext_vector_type(4))) float;

__device__ inline ushort f2bf(float f) {
    __hip_bfloat16 b = __float2bfloat16(f);
    return *reinterpret_cast<ushort*>(&b);
}
__device__ inline float bf2f(ushort u) {
    unsigned v = (unsigned)u << 16;
    union { unsigned u; float f; } c; c.u = v; return c.f;
}

// ---------------- Kernel 0: pre-split W1, W2 into hi/lo bf16 (layout unchanged: [col][k])
__global__ __launch_bounds__(256) void wsplit_kernel(
    const float* __restrict__ W1, const float* __restrict__ W2,
    ushort* __restrict__ W1h, ushort* __restrict__ W1l,
    ushort* __restrict__ W2h, ushort* __restrict__ W2l)
{
    const int bid = blockIdx.x;
    const float* src; ushort *dh, *dl; int base;
    if (bid < 64) { src = W1; dh = W1h; dl = W1l; base = bid * 1024; }
    else          { src = W2; dh = W2h; dl = W2l; base = (bid - 64) * 1024; }
    const int i = base + threadIdx.x * 4;
    float4 f = *reinterpret_cast<const float4*>(src + i);
    ushort h[4], lo[4];
    float fv[4] = {f.x, f.y, f.z, f.w};
#pragma unroll
    for (int j = 0; j < 4; ++j) {
        h[j] = f2bf(fv[j]);
        lo[j] = f2bf(fv[j] - bf2f(h[j]));
    }
    *reinterpret_cast<uint2*>(dh + i) = *reinterpret_cast<uint2*>(h);
    *reinterpret_cast<uint2*>(dl + i) = *reinterpret_cast<uint2*>(lo);
}

// ---------------- Kernel 1: split-bf16 MFMA MLP. Block = 32 rows x 128 cols, 4 waves.
// x = relu(s@W1^T + b1) @ W2^T + b2 ; xb = bf16(x); sqb = ||bf16(x)||^2
__global__ __launch_bounds__(256) void mlp_kernel(
    const float* __restrict__ s, const ushort* __restrict__ W1h,
    const ushort* __restrict__ W1l, const float* __restrict__ b1,
    const ushort* __restrict__ W2h, const ushort* __restrict__ W2l,
    const float* __restrict__ b2, __hip_bfloat16* __restrict__ xb,
    float* __restrict__ sqb)
{
    // s staging: [32 rows][32 k] bf16, slot-swizzled; double-buffered, hi+lo
    __shared__ __align__(16) ushort sbh[2][32 * 32];
    __shared__ __align__(16) ushort sbl[2][32 * 32];
    // h: [32 rows][128 k] bf16, slot-swizzled (16 slots/row), hi+lo
    __shared__ __align__(16) ushort hbh[32 * 128];
    __shared__ __align__(16) ushort hbl[32 * 128];
    __shared__ __align__(16) ushort xtile[32 * 128];
    __shared__ float sqpart[4 * 32];

    const int t = threadIdx.x;
    const int w = t >> 6, l = t & 63;
    const int lc = l & 15, c4 = l >> 4;      // frag coords: lc = col/row idx, c4 = k-subgroup
    const int rb = blockIdx.x * 32;
    const int cb = w * 32;                   // wave's 32-col slice

    // ---- staging coords: thread t handles 4 f32 of the [32][32] chunk
    const int srow = t >> 3, skq = t & 7;    // k = skq*4
    const int ssl = ((skq >> 1) + (srow >> 2)) & 3;
    const int sByte = srow * 64 + (ssl ^ (srow & 3)) * 16 + (skq & 1) * 8;
    const float* sgbase = s + (size_t)(rb + srow) * SD + skq * 4;

    float4 sf;
#define STAGE_LOAD_S(kt_) sf = *reinterpret_cast<const float4*>(sgbase + (kt_) * 32)
#define STAGE_WRITE_S(b_) do { \
    float fv_[4] = {sf.x, sf.y, sf.z, sf.w}; \
    ushort h_[4], lo_[4]; \
    _Pragma("unroll") \
    for (int j_ = 0; j_ < 4; ++j_) { \
        h_[j_] = f2bf(fv_[j_]); \
        lo_[j_] = f2bf(fv_[j_] - bf2f(h_[j_])); \
    } \
    *reinterpret_cast<uint2*>(reinterpret_cast<char*>(sbh[b_]) + sByte) = *reinterpret_cast<uint2*>(h_); \
    *reinterpret_cast<uint2*>(reinterpret_cast<char*>(sbl[b_]) + sByte) = *reinterpret_cast<uint2*>(lo_); \
} while (0)

    // ---- A-frag read addresses (bytes) for rt=0,1 from sbuf
    int aByte[2];
#pragma unroll
    for (int rt = 0; rt < 2; ++rt) {
        int row = rt * 16 + lc;
        int sl = ((c4 + (row >> 2)) & 3) ^ (row & 3);
        aByte[rt] = row * 64 + sl * 16;
    }

    // ---- W1 frag pointers (global, L2-resident): col = cb + ct*16 + lc
    const ushort* w1hp[2]; const ushort* w1lp[2];
#pragma unroll
    for (int ct = 0; ct < 2; ++ct) {
        int col = cb + ct * 16 + lc;
        w1hp[ct] = W1h + (size_t)col * SD + c4 * 8;
        w1lp[ct] = W1l + (size_t)col * SD + c4 * 8;
    }

    f32x4 acc1[2][2];
#pragma unroll
    for (int rt = 0; rt < 2; ++rt)
#pragma unroll
        for (int ct = 0; ct < 2; ++ct) acc1[rt][ct] = {0.f, 0.f, 0.f, 0.f};

    STAGE_LOAD_S(0);
    STAGE_WRITE_S(0);
    short8 bh[2], bl[2], nbh[2], nbl[2];
#pragma unroll
    for (int ct = 0; ct < 2; ++ct) {
        bh[ct] = *reinterpret_cast<const short8*>(w1hp[ct]);
        bl[ct] = *reinterpret_cast<const short8*>(w1lp[ct]);
    }

    for (int kt = 0; kt < 16; ++kt) {
        __syncthreads();                         // sbuf[kt&1] published
        if (kt < 15) STAGE_LOAD_S(kt + 1);
        short8 ah[2], al[2];
#pragma unroll
        for (int rt = 0; rt < 2; ++rt) {
            ah[rt] = *reinterpret_cast<const short8*>(
                reinterpret_cast<char*>(sbh[kt & 1]) + aByte[rt]);
            al[rt] = *reinterpret_cast<const short8*>(
                reinterpret_cast<char*>(sbl[kt & 1]) + aByte[rt]);
        }
        if (kt < 15) {
#pragma unroll
            for (int ct = 0; ct < 2; ++ct) {
                nbh[ct] = *reinterpret_cast<const short8*>(w1hp[ct] + (kt + 1) * 32);
                nbl[ct] = *reinterpret_cast<const short8*>(w1lp[ct] + (kt + 1) * 32);
            }
        }
#pragma unroll
        for (int rt = 0; rt < 2; ++rt)
#pragma unroll
            for (int ct = 0; ct < 2; ++ct) {
                acc1[rt][ct] = __builtin_amdgcn_mfma_f32_16x16x32_bf16(ah[rt], bh[ct], acc1[rt][ct], 0, 0, 0);
                acc1[rt][ct] = __builtin_amdgcn_mfma_f32_16x16x32_bf16(ah[rt], bl[ct], acc1[rt][ct], 0, 0, 0);
                acc1[rt][ct] = __builtin_amdgcn_mfma_f32_16x16x32_bf16(al[rt], bh[ct], acc1[rt][ct], 0, 0, 0);
            }
        if (kt < 15) {
            STAGE_WRITE_S((kt + 1) & 1);
#pragma unroll
            for (int ct = 0; ct < 2; ++ct) { bh[ct] = nbh[ct]; bl[ct] = nbl[ct]; }
        }
    }

    // ---- bias + relu + split -> hbuf (fragment layout, slot ^ (row&15))
    float b1v[2];
#pragma unroll
    for (int ct = 0; ct < 2; ++ct) b1v[ct] = b1[cb + ct * 16 + lc];
#pragma unroll
    for (int rt = 0; rt < 2; ++rt)
#pragma unroll
        for (int ct = 0; ct < 2; ++ct)
#pragma unroll
            for (int reg = 0; reg < 4; ++reg) {
                float v = fmaxf(acc1[rt][ct][reg] + b1v[ct], 0.f);
                ushort hh = f2bf(v);
                ushort hl = f2bf(v - bf2f(hh));
                int row = rt * 16 + c4 * 4 + reg;
                int kcol = cb + ct * 16 + lc;
                int sl = (kcol >> 3) ^ (row & 15);
                int byte = row * 256 + sl * 16 + (kcol & 7) * 2;
                *reinterpret_cast<ushort*>(reinterpret_cast<char*>(hbh) + byte) = hh;
                *reinterpret_cast<ushort*>(reinterpret_cast<char*>(hbl) + byte) = hl;
            }
    __syncthreads();

    // ---- layer 2: K = 128, 4 K-steps, h from LDS, W2 frags from global
    f32x4 acc2[2][2];
#pragma unroll
    for (int rt = 0; rt < 2; ++rt)
#pragma unroll
        for (int ct = 0; ct < 2; ++ct) acc2[rt][ct] = {0.f, 0.f, 0.f, 0.f};

#pragma unroll
    for (int kt = 0; kt < 4; ++kt) {
        short8 ah[2], al[2];
#pragma unroll
        for (int rt = 0; rt < 2; ++rt) {
            int row = rt * 16 + lc;
            int sl = (kt * 4 + c4) ^ (row & 15);
            int byte = row * 256 + sl * 16;
            ah[rt] = *reinterpret_cast<const short8*>(reinterpret_cast<char*>(hbh) + byte);
            al[rt] = *reinterpret_cast<const short8*>(reinterpret_cast<char*>(hbl) + byte);
        }
        short8 wh[2], wl[2];
#pragma unroll
        for (int ct = 0; ct < 2; ++ct) {
            int col = cb + ct * 16 + lc;
            wh[ct] = *reinterpret_cast<const short8*>(W2h + (size_t)col * HID + kt * 32 + c4 * 8);
            wl[ct] = *reinterpret_cast<const short8*>(W2l + (size_t)col * HID + kt * 32 + c4 * 8);
        }
#pragma unroll
        for (int rt = 0; rt < 2; ++rt)
#pragma unroll
            for (int ct = 0; ct < 2; ++ct) {
                acc2[rt][ct] = __builtin_amdgcn_mfma_f32_16x16x32_bf16(ah[rt], wh[ct], acc2[rt][ct], 0, 0, 0);
                acc2[rt][ct] = __builtin_amdgcn_mfma_f32_16x16x32_bf16(ah[rt], wl[ct], acc2[rt][ct], 0, 0, 0);
                acc2[rt][ct] = __builtin_amdgcn_mfma_f32_16x16x32_bf16(al[rt], wh[ct], acc2[rt][ct], 0, 0, 0);
            }
    }

    // ---- epilogue: +b2, round to bf16, sq of rounded, stage x
    float b2v[2];
#pragma unroll
    for (int ct = 0; ct < 2; ++ct) b2v[ct] = b2[cb + ct * 16 + lc];
    float p[8];
#pragma unroll
    for (int j = 0; j < 8; ++j) p[j] = 0.f;
#pragma unroll
    for (int rt = 0; rt < 2; ++rt)
#pragma unroll
        for (int ct = 0; ct < 2; ++ct)
#pragma unroll
            for (int reg = 0; reg < 4; ++reg) {
                float v = acc2[rt][ct][reg] + b2v[ct];
                ushort xv = f2bf(v);
                float xf = bf2f(xv);
                p[rt * 4 + reg] = fmaf(xf, xf, p[rt * 4 + reg]);
                int row = rt * 16 + c4 * 4 + reg;
                int e = cb + ct * 16 + lc;
                xtile[row * 128 + e] = xv;
            }
#pragma unroll
    for (int j = 0; j < 8; ++j) {
#pragma unroll
        for (int off = 8; off >= 1; off >>= 1) p[j] += __shfl_xor(p[j], off, 16);
    }
    if (lc == 0) {
#pragma unroll
        for (int rt = 0; rt < 2; ++rt)
#pragma unroll
            for (int reg = 0; reg < 4; ++reg)
                sqpart[w * 32 + rt * 16 + c4 * 4 + reg] = p[rt * 4 + reg];
    }
    __syncthreads();
    if (t < 32)
        sqb[rb + t] = sqpart[t] + sqpart[32 + t] + sqpart[64 + t] + sqpart[96 + t];
    // coalesced x store
    const short8* xsv = reinterpret_cast<const short8*>(xtile);
    short8* xg = reinterpret_cast<short8*>(reinterpret_cast<ushort*>(xb) + (size_t)rb * DE);
    xg[t] = xsv[t];
    xg[t + 256] = xsv[t + 256];
}

// ---------------- Kernel 2: per-row top-11 of d2' = sq[c] - 2*dot (unchanged from r3)
__global__ __launch_bounds__(256, 6) void knn_kernel(
    const ushort* __restrict__ xs, const float* __restrict__ sqb,
    float* __restrict__ part)
{
    __shared__ __align__(16) ushort lbuf[2][TILE * DE];

    const int bid = blockIdx.x;
    const int rid = bid >> 4, cid = bid & 15;
    const int t = threadIdx.x;
    const int w = t >> 6, l = t & 63;
    const int q16 = l & 15, lg = l >> 4;
    const int q = rid * 64 + w * 16 + q16;
    const int kk = lg * 8;
    const int cstart = cid * (NN / NSPLIT);

    short8 bq[4];
#pragma unroll
    for (int kb = 0; kb < 4; ++kb)
        bq[kb] = *reinterpret_cast<const short8*>(xs + (size_t)q * DE + kb * 32 + kk);

    float m[KP1];
#pragma unroll
    for (int j = 0; j < KP1; ++j) m[j] = 1e30f;

    auto ins = [&](float d2) {
#pragma unroll
        for (int j = KP1 - 1; j >= 1; --j)
            m[j] = __builtin_amdgcn_fmed3f(d2, m[j - 1], m[j]);
        m[0] = fminf(d2, m[0]);
    };

    const int s0 = t, s1 = t + 256;
    const int g0 = (s0 >> 4) * DE + (s0 & 15) * 8;
    const int g1 = (s1 >> 4) * DE + (s1 & 15) * 8;
    const int d0 = ((s0 >> 4) * 16 + ((s0 & 15) ^ ((s0 >> 4) & 7))) * 8;
    const int d1 = ((s1 >> 4) * 16 + ((s1 & 15) ^ ((s1 >> 4) & 7))) * 8;

    short8 vS0, vS1;
#define STAGE_LOAD(tt_) do { \
    const ushort* sb_ = xs + (size_t)(cstart + (tt_) * TILE) * DE; \
    vS0 = *reinterpret_cast<const short8*>(sb_ + g0); \
    vS1 = *reinterpret_cast<const short8*>(sb_ + g1); \
} while (0)
#define STAGE_WRITE(nb_) do { \
    *reinterpret_cast<short8*>(&lbuf[nb_][d0]) = vS0; \
    *reinterpret_cast<short8*>(&lbuf[nb_][d1]) = vS1; \
} while (0)

    STAGE_LOAD(0);
    STAGE_WRITE(0);

    for (int tt = 0; tt < NTILE; ++tt) {
        __syncthreads();
        if (tt + 1 < NTILE) STAGE_LOAD(tt + 1);

        const int c0 = cstart + tt * TILE;
        float4 sv0 = *reinterpret_cast<const float4*>(sqb + c0 + lg * 4);
        float4 sv1 = *reinterpret_cast<const float4*>(sqb + c0 + 16 + lg * 4);

        const ushort* lb = lbuf[tt & 1];
        short8 fa[4], fb[4];
#pragma unroll
        for (int kb = 0; kb < 4; ++kb) {
            int col = (kb * 4 + lg) ^ (q16 & 7);
            fa[kb] = *reinterpret_cast<const short8*>(lb + (q16 * 16 + col) * 8);
            fb[kb] = *reinterpret_cast<const short8*>(lb + ((16 + q16) * 16 + col) * 8);
        }
        f32x4 acc0 = {0.f, 0.f, 0.f, 0.f}, acc1 = {0.f, 0.f, 0.f, 0.f};
#pragma unroll
        for (int kb = 0; kb < 4; ++kb) {
            acc0 = __builtin_amdgcn_mfma_f32_16x16x32_bf16(fa[kb], bq[kb], acc0, 0, 0, 0);
            acc1 = __builtin_amdgcn_mfma_f32_16x16x32_bf16(fb[kb], bq[kb], acc1, 0, 0, 0);
        }
        ins(fmaf(-2.f, acc0[0], sv0.x));
        ins(fmaf(-2.f, acc0[1], sv0.y));
        ins(fmaf(-2.f, acc0[2], sv0.z));
        ins(fmaf(-2.f, acc0[3], sv0.w));
        ins(fmaf(-2.f, acc1[0], sv1.x));
        ins(fmaf(-2.f, acc1[1], sv1.y));
        ins(fmaf(-2.f, acc1[2], sv1.z));
        ins(fmaf(-2.f, acc1[3], sv1.w));

        if (tt + 1 < NTILE) STAGE_WRITE((tt + 1) & 1);
    }
#undef STAGE_LOAD
#undef STAGE_WRITE

    __syncthreads();
    float* mb = reinterpret_cast<float*>(lbuf);
#pragma unroll
    for (int j = 0; j < KP1; ++j)
        mb[((w * 4 + lg) * KP1 + j) * 16 + q16] = m[j];
    __syncthreads();
    if (lg == 0) {
#pragma unroll
        for (int g = 1; g < 4; ++g)
#pragma unroll
            for (int j = 0; j < KP1; ++j)
                ins(mb[((w * 4 + g) * KP1 + j) * 16 + q16]);
#pragma unroll
        for (int j = 0; j < KP1; ++j)
            part[(size_t)(cid * KP1 + j) * NN + q] = m[j];
    }
}

// ---------------- Kernel 3: merge 16 partial top-11 lists -> sumk[row]; block partial sums
__global__ __launch_bounds__(256) void merge_kernel(
    const float* __restrict__ part, const float* __restrict__ sqb,
    float* __restrict__ sumk, float* __restrict__ psum)
{
    const int row = blockIdx.x * 256 + threadIdx.x;
    float m[KP1];
#pragma unroll
    for (int j = 0; j < KP1; ++j) m[j] = 1e30f;
#pragma unroll
    for (int ch = 0; ch < NCHUNK; ++ch) {
#pragma unroll
        for (int j = 0; j < KP1; ++j) {
            float d2 = part[(size_t)(ch * KP1 + j) * NN + row];
#pragma unroll
            for (int jj = KP1 - 1; jj >= 1; --jj)
                m[jj] = __builtin_amdgcn_fmed3f(d2, m[jj - 1], m[jj]);
            m[0] = fminf(d2, m[0]);
        }
    }
    const float sqq = sqb[row];
    float sum = 0.f;
#pragma unroll
    for (int j = 1; j < KP1; ++j)
        sum += sqrtf(fmaxf(m[j] + sqq, 1e-12f));
    sumk[row] = sum;

    float p = sum;
#pragma unroll
    for (int off = 32; off >= 1; off >>= 1) p += __shfl_xor(p, off, 64);
    __shared__ float red[4];
    if ((threadIdx.x & 63) == 0) red[threadIdx.x >> 6] = p;
    __syncthreads();
    if (threadIdx.x == 0) psum[blockIdx.x] = red[0] + red[1] + red[2] + red[3];
}

// ---------------- Kernel 4: mean over 32 partials -> q = EPS * mean^2
__global__ void reduce_kernel(const float* __restrict__ psum, float* __restrict__ qv)
{
    const int t = threadIdx.x;
    float p = (t < 32) ? psum[t] : 0.f;
#pragma unroll
    for (int off = 32; off >= 1; off >>= 1) p += __shfl_xor(p, off, 64);
    if (t == 0) {
        float mean = p * (1.0f / NN);
        qv[0] = EPSF * mean * mean;
    }
}

// ---------------- Kernel 5: out = q / (s^2 + q)
__global__ __launch_bounds__(256) void final_kernel(
    const float* __restrict__ sumk, const float* __restrict__ qv,
    float* __restrict__ out)
{
    const int i = blockIdx.x * 256 + threadIdx.x;
    const float qq = qv[0];
    const float sv = sumk[i];
    out[i] = qq / (fmaf(sv, sv, qq));
}

extern "C" void kernel_launch(void* const* d_in, const int* in_sizes, int n_in,
                              void* d_out, int out_size, void* d_ws, size_t ws_size,
                              hipStream_t stream)
{
    const float* s  = (const float*)d_in[0];
    const float* W1 = (const float*)d_in[1];
    const float* b1 = (const float*)d_in[2];
    const float* W2 = (const float*)d_in[3];
    const float* b2 = (const float*)d_in[4];
    float* out = (float*)d_out;

    char* ws = (char*)d_ws;
    __hip_bfloat16* xb = (__hip_bfloat16*)ws;                       // 2 MB
    float* sqb  = (float*)(ws + (size_t)NN * DE * 2);               // 32 KB
    float* part = sqb + NN;                                         // 5.77 MB
    float* sumk = part + (size_t)NCHUNK * KP1 * NN;                 // 32 KB
    float* psum = sumk + NN;                                        // 128 B
    float* qv   = psum + 32;                                        // 4 B
    ushort* W1h = (ushort*)(qv + 1);                                // 128 KB
    ushort* W1l = W1h + (size_t)HID * SD;                           // 128 KB
    ushort* W2h = W1l + (size_t)HID * SD;                           // 32 KB
    ushort* W2l = W2h + (size_t)DE * HID;                           // 32 KB

    wsplit_kernel<<<80, 256, 0, stream>>>(W1, W2, W1h, W1l, W2h, W2l);
    mlp_kernel<<<NN / 32, 256, 0, stream>>>(s, W1h, W1l, b1, W2h, W2l, b2, xb, sqb);
    knn_kernel<<<(NN / 64) * NSPLIT, 256, 0, stream>>>((const ushort*)xb, sqb, part);
    merge_kernel<<<NN / 256, 256, 0, stream>>>(part, sqb, sumk, psum);
    reduce_kernel<<<1, 64, 0, stream>>>(psum, qv);
    final_kernel<<<NN / 256, 256, 0, stream>>>(sumk, qv, out);
}

// Round 5
// 79.530 us; speedup vs baseline: 3.6904x; 1.0785x over previous
//
#include <hip/hip_runtime.h>
#include <hip/hip_bf16.h>

#define NN 8192
#define SD 512
#define HID 128
#define DE 128
#define KP1 11
#define EPSF 0.001f
#define NSPLIT 16
#define NCHUNK NSPLIT        // 16 partial lists per row
#define TILE 64
#define NTILE ((NN / NSPLIT) / TILE)   // 8 tiles of 64 candidates per block

using short8 = __attribute__((ext_vector_type(8))) short;
using f32x4 = __attribute__((ext_vector_type(4))) float;

__device__ inline ushort f2bf(float f) {
    __hip_bfloat16 b = __float2bfloat16(f);
    return *reinterpret_cast<ushort*>(&b);
}
__device__ inline float bf2f(ushort u) {
    unsigned v = (unsigned)u << 16;
    union { unsigned u; float f; } c; c.u = v; return c.f;
}

// ---------------- Kernel 0: pre-split W1, W2 into hi/lo bf16 (layout unchanged: [col][k])
__global__ __launch_bounds__(256) void wsplit_kernel(
    const float* __restrict__ W1, const float* __restrict__ W2,
    ushort* __restrict__ W1h, ushort* __restrict__ W1l,
    ushort* __restrict__ W2h, ushort* __restrict__ W2l)
{
    const int bid = blockIdx.x;
    const float* src; ushort *dh, *dl; int base;
    if (bid < 64) { src = W1; dh = W1h; dl = W1l; base = bid * 1024; }
    else          { src = W2; dh = W2h; dl = W2l; base = (bid - 64) * 1024; }
    const int i = base + threadIdx.x * 4;
    float4 f = *reinterpret_cast<const float4*>(src + i);
    ushort h[4], lo[4];
    float fv[4] = {f.x, f.y, f.z, f.w};
#pragma unroll
    for (int j = 0; j < 4; ++j) {
        h[j] = f2bf(fv[j]);
        lo[j] = f2bf(fv[j] - bf2f(h[j]));
    }
    *reinterpret_cast<uint2*>(dh + i) = *reinterpret_cast<uint2*>(h);
    *reinterpret_cast<uint2*>(dl + i) = *reinterpret_cast<uint2*>(lo);
}

// ---------------- Kernel 1: split-bf16 MFMA MLP. Block = 32 rows x 128 cols, 4 waves.
__global__ __launch_bounds__(256) void mlp_kernel(
    const float* __restrict__ s, const ushort* __restrict__ W1h,
    const ushort* __restrict__ W1l, const float* __restrict__ b1,
    const ushort* __restrict__ W2h, const ushort* __restrict__ W2l,
    const float* __restrict__ b2, __hip_bfloat16* __restrict__ xb,
    float* __restrict__ sqb)
{
    __shared__ __align__(16) ushort sbh[2][32 * 32];
    __shared__ __align__(16) ushort sbl[2][32 * 32];
    __shared__ __align__(16) ushort hbh[32 * 128];
    __shared__ __align__(16) ushort hbl[32 * 128];
    __shared__ __align__(16) ushort xtile[32 * 128];
    __shared__ float sqpart[4 * 32];

    const int t = threadIdx.x;
    const int w = t >> 6, l = t & 63;
    const int lc = l & 15, c4 = l >> 4;
    const int rb = blockIdx.x * 32;
    const int cb = w * 32;

    const int srow = t >> 3, skq = t & 7;
    const int ssl = ((skq >> 1) + (srow >> 2)) & 3;
    const int sByte = srow * 64 + (ssl ^ (srow & 3)) * 16 + (skq & 1) * 8;
    const float* sgbase = s + (size_t)(rb + srow) * SD + skq * 4;

    float4 sf;
#define STAGE_LOAD_S(kt_) sf = *reinterpret_cast<const float4*>(sgbase + (kt_) * 32)
#define STAGE_WRITE_S(b_) do { \
    float fv_[4] = {sf.x, sf.y, sf.z, sf.w}; \
    ushort h_[4], lo_[4]; \
    _Pragma("unroll") \
    for (int j_ = 0; j_ < 4; ++j_) { \
        h_[j_] = f2bf(fv_[j_]); \
        lo_[j_] = f2bf(fv_[j_] - bf2f(h_[j_])); \
    } \
    *reinterpret_cast<uint2*>(reinterpret_cast<char*>(sbh[b_]) + sByte) = *reinterpret_cast<uint2*>(h_); \
    *reinterpret_cast<uint2*>(reinterpret_cast<char*>(sbl[b_]) + sByte) = *reinterpret_cast<uint2*>(lo_); \
} while (0)

    int aByte[2];
#pragma unroll
    for (int rt = 0; rt < 2; ++rt) {
        int row = rt * 16 + lc;
        int sl = ((c4 + (row >> 2)) & 3) ^ (row & 3);
        aByte[rt] = row * 64 + sl * 16;
    }

    const ushort* w1hp[2]; const ushort* w1lp[2];
#pragma unroll
    for (int ct = 0; ct < 2; ++ct) {
        int col = cb + ct * 16 + lc;
        w1hp[ct] = W1h + (size_t)col * SD + c4 * 8;
        w1lp[ct] = W1l + (size_t)col * SD + c4 * 8;
    }

    f32x4 acc1[2][2];
#pragma unroll
    for (int rt = 0; rt < 2; ++rt)
#pragma unroll
        for (int ct = 0; ct < 2; ++ct) acc1[rt][ct] = {0.f, 0.f, 0.f, 0.f};

    STAGE_LOAD_S(0);
    STAGE_WRITE_S(0);
    short8 bh[2], bl[2], nbh[2], nbl[2];
#pragma unroll
    for (int ct = 0; ct < 2; ++ct) {
        bh[ct] = *reinterpret_cast<const short8*>(w1hp[ct]);
        bl[ct] = *reinterpret_cast<const short8*>(w1lp[ct]);
    }

    for (int kt = 0; kt < 16; ++kt) {
        __syncthreads();
        if (kt < 15) STAGE_LOAD_S(kt + 1);
        short8 ah[2], al[2];
#pragma unroll
        for (int rt = 0; rt < 2; ++rt) {
            ah[rt] = *reinterpret_cast<const short8*>(
                reinterpret_cast<char*>(sbh[kt & 1]) + aByte[rt]);
            al[rt] = *reinterpret_cast<const short8*>(
                reinterpret_cast<char*>(sbl[kt & 1]) + aByte[rt]);
        }
        if (kt < 15) {
#pragma unroll
            for (int ct = 0; ct < 2; ++ct) {
                nbh[ct] = *reinterpret_cast<const short8*>(w1hp[ct] + (kt + 1) * 32);
                nbl[ct] = *reinterpret_cast<const short8*>(w1lp[ct] + (kt + 1) * 32);
            }
        }
#pragma unroll
        for (int rt = 0; rt < 2; ++rt)
#pragma unroll
            for (int ct = 0; ct < 2; ++ct) {
                acc1[rt][ct] = __builtin_amdgcn_mfma_f32_16x16x32_bf16(ah[rt], bh[ct], acc1[rt][ct], 0, 0, 0);
                acc1[rt][ct] = __builtin_amdgcn_mfma_f32_16x16x32_bf16(ah[rt], bl[ct], acc1[rt][ct], 0, 0, 0);
                acc1[rt][ct] = __builtin_amdgcn_mfma_f32_16x16x32_bf16(al[rt], bh[ct], acc1[rt][ct], 0, 0, 0);
            }
        if (kt < 15) {
            STAGE_WRITE_S((kt + 1) & 1);
#pragma unroll
            for (int ct = 0; ct < 2; ++ct) { bh[ct] = nbh[ct]; bl[ct] = nbl[ct]; }
        }
    }

    float b1v[2];
#pragma unroll
    for (int ct = 0; ct < 2; ++ct) b1v[ct] = b1[cb + ct * 16 + lc];
#pragma unroll
    for (int rt = 0; rt < 2; ++rt)
#pragma unroll
        for (int ct = 0; ct < 2; ++ct)
#pragma unroll
            for (int reg = 0; reg < 4; ++reg) {
                float v = fmaxf(acc1[rt][ct][reg] + b1v[ct], 0.f);
                ushort hh = f2bf(v);
                ushort hl = f2bf(v - bf2f(hh));
                int row = rt * 16 + c4 * 4 + reg;
                int kcol = cb + ct * 16 + lc;
                int sl = (kcol >> 3) ^ (row & 15);
                int byte = row * 256 + sl * 16 + (kcol & 7) * 2;
                *reinterpret_cast<ushort*>(reinterpret_cast<char*>(hbh) + byte) = hh;
                *reinterpret_cast<ushort*>(reinterpret_cast<char*>(hbl) + byte) = hl;
            }
    __syncthreads();

    f32x4 acc2[2][2];
#pragma unroll
    for (int rt = 0; rt < 2; ++rt)
#pragma unroll
        for (int ct = 0; ct < 2; ++ct) acc2[rt][ct] = {0.f, 0.f, 0.f, 0.f};

#pragma unroll
    for (int kt = 0; kt < 4; ++kt) {
        short8 ah[2], al[2];
#pragma unroll
        for (int rt = 0; rt < 2; ++rt) {
            int row = rt * 16 + lc;
            int sl = (kt * 4 + c4) ^ (row & 15);
            int byte = row * 256 + sl * 16;
            ah[rt] = *reinterpret_cast<const short8*>(reinterpret_cast<char*>(hbh) + byte);
            al[rt] = *reinterpret_cast<const short8*>(reinterpret_cast<char*>(hbl) + byte);
        }
        short8 wh[2], wl[2];
#pragma unroll
        for (int ct = 0; ct < 2; ++ct) {
            int col = cb + ct * 16 + lc;
            wh[ct] = *reinterpret_cast<const short8*>(W2h + (size_t)col * HID + kt * 32 + c4 * 8);
            wl[ct] = *reinterpret_cast<const short8*>(W2l + (size_t)col * HID + kt * 32 + c4 * 8);
        }
#pragma unroll
        for (int rt = 0; rt < 2; ++rt)
#pragma unroll
            for (int ct = 0; ct < 2; ++ct) {
                acc2[rt][ct] = __builtin_amdgcn_mfma_f32_16x16x32_bf16(ah[rt], wh[ct], acc2[rt][ct], 0, 0, 0);
                acc2[rt][ct] = __builtin_amdgcn_mfma_f32_16x16x32_bf16(ah[rt], wl[ct], acc2[rt][ct], 0, 0, 0);
                acc2[rt][ct] = __builtin_amdgcn_mfma_f32_16x16x32_bf16(al[rt], wh[ct], acc2[rt][ct], 0, 0, 0);
            }
    }

    float b2v[2];
#pragma unroll
    for (int ct = 0; ct < 2; ++ct) b2v[ct] = b2[cb + ct * 16 + lc];
    float p[8];
#pragma unroll
    for (int j = 0; j < 8; ++j) p[j] = 0.f;
#pragma unroll
    for (int rt = 0; rt < 2; ++rt)
#pragma unroll
        for (int ct = 0; ct < 2; ++ct)
#pragma unroll
            for (int reg = 0; reg < 4; ++reg) {
                float v = acc2[rt][ct][reg] + b2v[ct];
                ushort xv = f2bf(v);
                float xf = bf2f(xv);
                p[rt * 4 + reg] = fmaf(xf, xf, p[rt * 4 + reg]);
                int row = rt * 16 + c4 * 4 + reg;
                int e = cb + ct * 16 + lc;
                xtile[row * 128 + e] = xv;
            }
#pragma unroll
    for (int j = 0; j < 8; ++j) {
#pragma unroll
        for (int off = 8; off >= 1; off >>= 1) p[j] += __shfl_xor(p[j], off, 16);
    }
    if (lc == 0) {
#pragma unroll
        for (int rt = 0; rt < 2; ++rt)
#pragma unroll
            for (int reg = 0; reg < 4; ++reg)
                sqpart[w * 32 + rt * 16 + c4 * 4 + reg] = p[rt * 4 + reg];
    }
    __syncthreads();
    if (t < 32)
        sqb[rb + t] = sqpart[t] + sqpart[32 + t] + sqpart[64 + t] + sqpart[96 + t];
    const short8* xsv = reinterpret_cast<const short8*>(xtile);
    short8* xg = reinterpret_cast<short8*>(reinterpret_cast<ushort*>(xb) + (size_t)rb * DE);
    xg[t] = xsv[t];
    xg[t + 256] = xsv[t + 256];
}

// ---------------- Kernel 2: per-row top-11 of d2' = sq[c] - 2*dot.
// 32 queries/wave (2 MFMA q-subtiles), 64-cand LDS tiles (double-buffered,
// XOR-swizzled), sq staged in LDS, med3 sorted insert.
__global__ __launch_bounds__(256) void knn_kernel(
    const ushort* __restrict__ xs, const float* __restrict__ sqb,
    float* __restrict__ part)
{
    __shared__ __align__(16) ushort lbuf[2][TILE * DE];   // 2 x 16KB
    __shared__ __align__(16) float sqs[NN / NSPLIT];      // 2KB

    const int bid = blockIdx.x;              // 1024 = 64 row-groups x 16 cand-splits
    const int rid = bid >> 4, cid = bid & 15;
    const int t = threadIdx.x;
    const int w = t >> 6, l = t & 63;
    const int q16 = l & 15, lg = l >> 4;
    const int kk = lg * 8;
    const int qb = rid * 128 + w * 32;
    const int cstart = cid * (NN / NSPLIT);  // 512 candidates per block

    // B-frags for the wave's 2 query sub-tiles (held in regs)
    short8 bq[2][4];
#pragma unroll
    for (int qs = 0; qs < 2; ++qs)
#pragma unroll
        for (int kb = 0; kb < 4; ++kb)
            bq[qs][kb] = *reinterpret_cast<const short8*>(
                xs + (size_t)(qb + qs * 16 + q16) * DE + kb * 32 + kk);

    float m[2][KP1];
#pragma unroll
    for (int qs = 0; qs < 2; ++qs)
#pragma unroll
        for (int j = 0; j < KP1; ++j) m[qs][j] = 1e30f;

#define INS(qs_, v_) do { \
    float d2_ = (v_); \
    _Pragma("unroll") \
    for (int j_ = KP1 - 1; j_ >= 1; --j_) \
        m[qs_][j_] = __builtin_amdgcn_fmed3f(d2_, m[qs_][j_ - 1], m[qs_][j_]); \
    m[qs_][0] = fminf(d2_, m[qs_][0]); \
} while (0)

    // stage sq for the block's candidate range once
    if (t < 128)
        reinterpret_cast<float4*>(sqs)[t] =
            reinterpret_cast<const float4*>(sqb + cstart)[t];

    // staging: thread t owns 4 16B slots s = t + 256*i of the 1024-slot tile
    int gIdx[4], dIdx[4];
#pragma unroll
    for (int i = 0; i < 4; ++i) {
        int sl = t + 256 * i;
        int row = sl >> 4, col = sl & 15;
        gIdx[i] = row * DE + col * 8;                       // ushort units
        dIdx[i] = (row * 16 + (col ^ (row & 7))) * 8;
    }
    // A-frag base indices (row = q16 within a 16-cand subtile)
    int aIdx[4];
#pragma unroll
    for (int kb = 0; kb < 4; ++kb)
        aIdx[kb] = (q16 * 16 + ((kb * 4 + lg) ^ (q16 & 7))) * 8;

    short8 st[4];
#define STAGE_LOAD(tt_) do { \
    const ushort* sb_ = xs + (size_t)(cstart + (tt_) * TILE) * DE; \
    _Pragma("unroll") \
    for (int i_ = 0; i_ < 4; ++i_) \
        st[i_] = *reinterpret_cast<const short8*>(sb_ + gIdx[i_]); \
} while (0)
#define STAGE_WRITE(nb_) do { \
    _Pragma("unroll") \
    for (int i_ = 0; i_ < 4; ++i_) \
        *reinterpret_cast<short8*>(&lbuf[nb_][dIdx[i_]]) = st[i_]; \
} while (0)

    STAGE_LOAD(0);
    STAGE_WRITE(0);

    for (int tt = 0; tt < NTILE; ++tt) {
        __syncthreads();                     // publishes lbuf[tt&1] (and sqs on tt=0)
        if (tt + 1 < NTILE) STAGE_LOAD(tt + 1);
        const ushort* lb = lbuf[tt & 1];
#pragma unroll
        for (int cs = 0; cs < 4; ++cs) {     // 16-cand subtiles
            short8 fa[4];
#pragma unroll
            for (int kb = 0; kb < 4; ++kb)
                fa[kb] = *reinterpret_cast<const short8*>(lb + cs * 2048 + aIdx[kb]);
            float4 sv = *reinterpret_cast<const float4*>(sqs + tt * TILE + cs * 16 + lg * 4);
#pragma unroll
            for (int qs = 0; qs < 2; ++qs) {
                f32x4 acc = {0.f, 0.f, 0.f, 0.f};
#pragma unroll
                for (int kb = 0; kb < 4; ++kb)
                    acc = __builtin_amdgcn_mfma_f32_16x16x32_bf16(fa[kb], bq[qs][kb], acc, 0, 0, 0);
                INS(qs, fmaf(-2.f, acc[0], sv.x));
                INS(qs, fmaf(-2.f, acc[1], sv.y));
                INS(qs, fmaf(-2.f, acc[2], sv.z));
                INS(qs, fmaf(-2.f, acc[3], sv.w));
            }
        }
        if (tt + 1 < NTILE) STAGE_WRITE((tt + 1) & 1);  // buffer freed by this iter's sync
    }
#undef STAGE_LOAD
#undef STAGE_WRITE
#undef INS

    // ---- in-kernel lane-group merge: 4 lists per query -> 1 list per (q, cid)
    __syncthreads();                          // all waves done reading lbuf
    float* mb = reinterpret_cast<float*>(lbuf);   // [4w][2qs][4lg][11][16] floats
#pragma unroll
    for (int qs = 0; qs < 2; ++qs)
#pragma unroll
        for (int j = 0; j < KP1; ++j)
            mb[(((w * 2 + qs) * 4 + lg) * KP1 + j) * 16 + q16] = m[qs][j];
    __syncthreads();
    if (l < 32) {
        const int qs = l >> 4, qq = l & 15;
        float mm[KP1];
#pragma unroll
        for (int j = 0; j < KP1; ++j)
            mm[j] = mb[(((w * 2 + qs) * 4 + 0) * KP1 + j) * 16 + qq];
#pragma unroll
        for (int g = 1; g < 4; ++g)
#pragma unroll
            for (int j = 0; j < KP1; ++j) {
                float d2 = mb[(((w * 2 + qs) * 4 + g) * KP1 + j) * 16 + qq];
#pragma unroll
                for (int jj = KP1 - 1; jj >= 1; --jj)
                    mm[jj] = __builtin_amdgcn_fmed3f(d2, mm[jj - 1], mm[jj]);
                mm[0] = fminf(d2, mm[0]);
            }
        const int q = qb + qs * 16 + qq;
#pragma unroll
        for (int j = 0; j < KP1; ++j)
            part[(size_t)(cid * KP1 + j) * NN + q] = mm[j];
    }
}

// ---------------- Kernel 3: merge 16 partial top-11 lists -> sumk[row]; block partial sums
__global__ __launch_bounds__(256) void merge_kernel(
    const float* __restrict__ part, const float* __restrict__ sqb,
    float* __restrict__ sumk, float* __restrict__ psum)
{
    const int row = blockIdx.x * 256 + threadIdx.x;
    float m[KP1];
#pragma unroll
    for (int j = 0; j < KP1; ++j) m[j] = 1e30f;
#pragma unroll
    for (int ch = 0; ch < NCHUNK; ++ch) {
#pragma unroll
        for (int j = 0; j < KP1; ++j) {
            float d2 = part[(size_t)(ch * KP1 + j) * NN + row];
#pragma unroll
            for (int jj = KP1 - 1; jj >= 1; --jj)
                m[jj] = __builtin_amdgcn_fmed3f(d2, m[jj - 1], m[jj]);
            m[0] = fminf(d2, m[0]);
        }
    }
    const float sqq = sqb[row];
    float sum = 0.f;
#pragma unroll
    for (int j = 1; j < KP1; ++j)
        sum += sqrtf(fmaxf(m[j] + sqq, 1e-12f));
    sumk[row] = sum;

    float p = sum;
#pragma unroll
    for (int off = 32; off >= 1; off >>= 1) p += __shfl_xor(p, off, 64);
    __shared__ float red[4];
    if ((threadIdx.x & 63) == 0) red[threadIdx.x >> 6] = p;
    __syncthreads();
    if (threadIdx.x == 0) psum[blockIdx.x] = red[0] + red[1] + red[2] + red[3];
}

// ---------------- Kernel 4: mean over 32 partials -> q = EPS * mean^2
__global__ void reduce_kernel(const float* __restrict__ psum, float* __restrict__ qv)
{
    const int t = threadIdx.x;
    float p = (t < 32) ? psum[t] : 0.f;
#pragma unroll
    for (int off = 32; off >= 1; off >>= 1) p += __shfl_xor(p, off, 64);
    if (t == 0) {
        float mean = p * (1.0f / NN);
        qv[0] = EPSF * mean * mean;
    }
}

// ---------------- Kernel 5: out = q / (s^2 + q)
__global__ __launch_bounds__(256) void final_kernel(
    const float* __restrict__ sumk, const float* __restrict__ qv,
    float* __restrict__ out)
{
    const int i = blockIdx.x * 256 + threadIdx.x;
    const float qq = qv[0];
    const float sv = sumk[i];
    out[i] = qq / (fmaf(sv, sv, qq));
}

extern "C" void kernel_launch(void* const* d_in, const int* in_sizes, int n_in,
                              void* d_out, int out_size, void* d_ws, size_t ws_size,
                              hipStream_t stream)
{
    const float* s  = (const float*)d_in[0];
    const float* W1 = (const float*)d_in[1];
    const float* b1 = (const float*)d_in[2];
    const float* W2 = (const float*)d_in[3];
    const float* b2 = (const float*)d_in[4];
    float* out = (float*)d_out;

    char* ws = (char*)d_ws;
    __hip_bfloat16* xb = (__hip_bfloat16*)ws;                       // 2 MB
    float* sqb  = (float*)(ws + (size_t)NN * DE * 2);               // 32 KB
    float* part = sqb + NN;                                         // 5.77 MB
    float* sumk = part + (size_t)NCHUNK * KP1 * NN;                 // 32 KB
    float* psum = sumk + NN;                                        // 128 B
    float* qv   = psum + 32;                                        // 4 B
    ushort* W1h = (ushort*)(qv + 1);                                // 128 KB
    ushort* W1l = W1h + (size_t)HID * SD;                           // 128 KB
    ushort* W2h = W1l + (size_t)HID * SD;                           // 32 KB
    ushort* W2l = W2h + (size_t)DE * HID;                           // 32 KB

    wsplit_kernel<<<80, 256, 0, stream>>>(W1, W2, W1h, W1l, W2h, W2l);
    mlp_kernel<<<NN / 32, 256, 0, stream>>>(s, W1h, W1l, b1, W2h, W2l, b2, xb, sqb);
    knn_kernel<<<(NN / 128) * NSPLIT, 256, 0, stream>>>((const ushort*)xb, sqb, part);
    merge_kernel<<<NN / 256, 256, 0, stream>>>(part, sqb, sumk, psum);
    reduce_kernel<<<1, 64, 0, stream>>>(psum, qv);
    final_kernel<<<NN / 256, 256, 0, stream>>>(sumk, qv, out);
}